// Round 2
// baseline (220.061 us; speedup 1.0000x reference)
//
#include <hip/hip_runtime.h>

// Conv2d: N=32, Cin=128, H=W=56, Cout=256, K=3, stride=1, pad=1. fp32 in/out.
// Strategy: bf16 implicit GEMM via MFMA (threshold is bf16-grade: 7.6e-2).
//   Pass 1: x (NCHW f32) -> Xt (NHWC bf16)  [LDS transpose, coalesced]
//   Pass 2: w (OIHW f32) -> Wt[oc][pos][ic] bf16
//   Pass 3: implicit GEMM, M=256(oc) x N=100352(pix) x K=1152(9pos*128ic)
//           128x128 tile, BK=32, 4 waves, mfma_f32_16x16x32_bf16

typedef __attribute__((ext_vector_type(8))) short short8;   // 8 bf16
typedef __attribute__((ext_vector_type(4))) float f32x4;

#define HWSZ 56
#define HW2 3136           // 56*56
#define INC 128
#define OUTC 256
#define NBATCH 32
#define NPIX (NBATCH * HW2)   // 100352
#define KTOT 1152          // 9*128
#define XT_ELEMS 12845056  // 32*3136*128

__device__ __forceinline__ unsigned short f2b(float f) {
    union { float f; unsigned u; } v; v.f = f;
    unsigned r = v.u + 0x7fffu + ((v.u >> 16) & 1u);   // RNE
    return (unsigned short)(r >> 16);
}

// ---- Pass 1: x[n][c][h][w] f32 -> xt[n][h][w][c] bf16 ----
__global__ __launch_bounds__(256) void xt_kernel(const float* __restrict__ x,
                                                 unsigned short* __restrict__ xt) {
    __shared__ float tile[128][65];   // [c][hw], pad 65 to break pow2 stride
    const int b = blockIdx.x;         // 32 * 49 = 1568 blocks
    const int n = b / 49;
    const int hw0 = (b - n * 49) * 64;
    const int t = threadIdx.x;

    const float* xp = x + (size_t)n * (INC * HW2) + hw0;
    const int c_base = t >> 4;          // 0..15
    const int hwo = (t & 15) * 4;       // 0..60
#pragma unroll
    for (int j = 0; j < 8; ++j) {
        const int c = j * 16 + c_base;
        const f32x4 v = *reinterpret_cast<const f32x4*>(xp + c * HW2 + hwo);
        tile[c][hwo + 0] = v[0];
        tile[c][hwo + 1] = v[1];
        tile[c][hwo + 2] = v[2];
        tile[c][hwo + 3] = v[3];
    }
    __syncthreads();
    const int hw = t >> 2;              // 0..63
    const int c0 = (t & 3) * 32;
    unsigned short* dst = xt + ((size_t)(n * HW2 + hw0 + hw)) * INC + c0;
#pragma unroll
    for (int g = 0; g < 4; ++g) {
        short8 v;
#pragma unroll
        for (int e = 0; e < 8; ++e) v[e] = (short)f2b(tile[c0 + g * 8 + e][hw]);
        reinterpret_cast<short8*>(dst)[g] = v;
    }
}

// ---- Pass 2: w[oc][ic][kh][kw] f32 -> wt[oc][pos][ic] bf16 ----
__global__ __launch_bounds__(256) void wt_kernel(const float* __restrict__ w,
                                                 unsigned short* __restrict__ wt) {
    const int tid = blockIdx.x * 256 + threadIdx.x;   // 1152 blocks -> 294912
    const int oc = tid / KTOT;
    const int r = tid - oc * KTOT;
    const int pos = r >> 7;
    const int ic = r & 127;
    wt[tid] = f2b(w[oc * KTOT + ic * 9 + pos]);
}

// ---- Pass 3: main implicit GEMM ----
__global__ __launch_bounds__(256, 2) void conv_main(const unsigned short* __restrict__ xt,
                                                    const unsigned short* __restrict__ wt,
                                                    const float* __restrict__ bias,
                                                    float* __restrict__ out) {
    __shared__ unsigned short As[128][40];   // [oc][k] pad->80B stride (5*16B)
    __shared__ unsigned short Bs[128][40];   // [pix][k]

    // XCD-bijective swizzle: 1568 = 8 * 196; same-pixel oc-pair adjacent per XCD
    const int bid = blockIdx.x;
    const int work = (bid & 7) * 196 + (bid >> 3);
    const int oc0 = (work & 1) * 128;
    const int P0 = (work >> 1) * 128;

    const int t = threadIdx.x;
    const int lane = t & 63;
    const int wid = t >> 6;
    const int wr = wid >> 1;     // wave row (oc half)
    const int wc = wid & 1;      // wave col (pix half)
    const int fr = lane & 15;
    const int fq = lane >> 4;

    // staging assignment: thread -> (row = t/2, k-col = (t&1)*16 .. +16)
    const int srow = t >> 1;
    const int scol = (t & 1) * 16;
    const unsigned short* wt_base = wt + (oc0 + srow) * KTOT + scol;

    const int P = P0 + srow;
    const int n = P / HW2;
    const int hw = P - n * HW2;
    const int oh = hw / HWSZ;
    const int ow = hw - oh * HWSZ;
    const unsigned short* xt_img = xt + (size_t)n * (HW2 * INC);

    f32x4 acc[4][4];
#pragma unroll
    for (int i = 0; i < 4; ++i)
#pragma unroll
        for (int j = 0; j < 4; ++j) {
            f32x4 z = {0.f, 0.f, 0.f, 0.f};
            acc[i][j] = z;
        }

    const short8 zero8 = {0, 0, 0, 0, 0, 0, 0, 0};
    short8 ra0, ra1, rb0, rb1;

    auto load_tiles = [&](int s, short8& a0, short8& a1, short8& b0, short8& b1) {
        const int pos = s >> 2;           // 0..8 (kh*3+kw)
        const int icc = s & 3;            // ic chunk of 32
        const short8* ap = reinterpret_cast<const short8*>(wt_base + pos * 128 + icc * 32);
        a0 = ap[0];
        a1 = ap[1];
        const int kh = pos / 3;
        const int kw = pos - kh * 3;
        const int ih = oh + kh - 1;
        const int iw = ow + kw - 1;
        if ((unsigned)ih < (unsigned)HWSZ && (unsigned)iw < (unsigned)HWSZ) {
            const short8* bp = reinterpret_cast<const short8*>(
                xt_img + (ih * HWSZ + iw) * INC + icc * 32 + scol);
            b0 = bp[0];
            b1 = bp[1];
        } else {
            b0 = zero8;
            b1 = zero8;
        }
    };

    load_tiles(0, ra0, ra1, rb0, rb1);

    for (int s = 0; s < 36; ++s) {
        __syncthreads();   // all reads of LDS from prev step done
        *reinterpret_cast<short8*>(&As[srow][scol]) = ra0;
        *reinterpret_cast<short8*>(&As[srow][scol + 8]) = ra1;
        *reinterpret_cast<short8*>(&Bs[srow][scol]) = rb0;
        *reinterpret_cast<short8*>(&Bs[srow][scol + 8]) = rb1;
        __syncthreads();   // LDS tile ready
        if (s < 35) load_tiles(s + 1, ra0, ra1, rb0, rb1);  // overlap with MFMA

        short8 af[4], bf[4];
#pragma unroll
        for (int mi = 0; mi < 4; ++mi)
            af[mi] = *reinterpret_cast<const short8*>(&As[wr * 64 + mi * 16 + fr][fq * 8]);
#pragma unroll
        for (int ni = 0; ni < 4; ++ni)
            bf[ni] = *reinterpret_cast<const short8*>(&Bs[wc * 64 + ni * 16 + fr][fq * 8]);
#pragma unroll
        for (int mi = 0; mi < 4; ++mi)
#pragma unroll
            for (int ni = 0; ni < 4; ++ni)
                acc[mi][ni] = __builtin_amdgcn_mfma_f32_16x16x32_bf16(af[mi], bf[ni],
                                                                      acc[mi][ni], 0, 0, 0);
    }

    // epilogue: D row(oc) = fq*4+r, col(pix) = fr   [m89-verified C/D layout]
    float bmr[4][4];
#pragma unroll
    for (int mi = 0; mi < 4; ++mi)
#pragma unroll
        for (int r = 0; r < 4; ++r)
            bmr[mi][r] = bias[oc0 + wr * 64 + mi * 16 + fq * 4 + r];

#pragma unroll
    for (int ni = 0; ni < 4; ++ni) {
        const int Pp = P0 + wc * 64 + ni * 16 + fr;
        const int nn = Pp / HW2;
        const int hwp = Pp - nn * HW2;
        float* op = out + (size_t)nn * (OUTC * HW2) + hwp;
#pragma unroll
        for (int mi = 0; mi < 4; ++mi)
#pragma unroll
            for (int r = 0; r < 4; ++r) {
                const int oc = oc0 + wr * 64 + mi * 16 + fq * 4 + r;
                op[oc * HW2] = acc[mi][ni][r] + bmr[mi][r];
            }
    }
}

extern "C" void kernel_launch(void* const* d_in, const int* in_sizes, int n_in,
                              void* d_out, int out_size, void* d_ws, size_t ws_size,
                              hipStream_t stream) {
    const float* x = (const float*)d_in[0];
    const float* w = (const float*)d_in[1];
    const float* bias = (const float*)d_in[2];
    float* out = (float*)d_out;

    // workspace: Xt (25,690,112 B) then Wt (589,824 B) ~ 26.3 MB total
    unsigned short* xt = (unsigned short*)d_ws;
    unsigned short* wt = xt + XT_ELEMS;

    xt_kernel<<<1568, 256, 0, stream>>>(x, xt);
    wt_kernel<<<1152, 256, 0, stream>>>(w, wt);
    conv_main<<<1568, 256, 0, stream>>>(xt, wt, bias, out);
}

// Round 4
// 204.341 us; speedup vs baseline: 1.0769x; 1.0769x over previous
//
#include <hip/hip_runtime.h>

// Conv2d: N=32, Cin=128, H=W=56, Cout=256, K=3, s=1, p=1. fp32 in/out, bf16 MFMA.
// R3: halo-padded Xt + fragment-ordered swizzled Wt panels -> global_load_lds
//     staging, conflict-free lane-linear ds_read_b128, 2-phase dbuf pipeline.

typedef __attribute__((ext_vector_type(8))) short short8;   // 8 bf16
typedef __attribute__((ext_vector_type(4))) float f32x4;
typedef unsigned short ushort_t;

#define HWSZ 56
#define HW2 3136
#define INC 128
#define OUTC 256
#define NPIX 100352
#define PADW 58
#define XT_ELEMS 13778944          // 32*58*58*128
#define XT_BYTES 27557888

__device__ __forceinline__ ushort_t f2b(float f) {
    union { float f; unsigned u; } v; v.f = f;
    unsigned r = v.u + 0x7fffu + ((v.u >> 16) & 1u);   // RNE
    return (ushort_t)(r >> 16);
}

__device__ __forceinline__ void glds16(const void* g, void* l) {
    __builtin_amdgcn_global_load_lds(
        (const __attribute__((address_space(1))) unsigned*)g,
        (__attribute__((address_space(3))) unsigned*)l, 16, 0, 0);
}

// ---- Pass 1: x[n][c][h][w] f32 -> xt[n][h+1][w+1][c] bf16 (halo pre-zeroed) ----
__global__ __launch_bounds__(256) void xt_kernel(const float* __restrict__ x,
                                                 ushort_t* __restrict__ xt) {
    __shared__ float tile[128][65];
    const int b = blockIdx.x;          // 32*49
    const int n = b / 49;
    const int hw0 = (b - n * 49) * 64;
    const int t = threadIdx.x;

    const float* xp = x + (size_t)n * (INC * HW2) + hw0;
    const int c_base = t >> 4;
    const int hwo = (t & 15) * 4;
#pragma unroll
    for (int j = 0; j < 8; ++j) {
        const int c = j * 16 + c_base;
        const f32x4 v = *reinterpret_cast<const f32x4*>(xp + c * HW2 + hwo);
        tile[c][hwo + 0] = v[0];
        tile[c][hwo + 1] = v[1];
        tile[c][hwo + 2] = v[2];
        tile[c][hwo + 3] = v[3];
    }
    __syncthreads();
    const int hw = t >> 2;
    const int q = t & 3;
    const int P = hw0 + hw;
    const int oh = P / HWSZ;
    const int ow = P - oh * HWSZ;
    ushort_t* dst = xt + (((size_t)n * PADW + oh + 1) * PADW + (ow + 1)) * INC;
#pragma unroll
    for (int g = 0; g < 4; ++g) {      // thread covers channels g*32 + q*8 + e
        short8 v;
#pragma unroll
        for (int e = 0; e < 8; ++e) v[e] = (short)f2b(tile[g * 32 + q * 8 + e][hw]);
        *reinterpret_cast<short8*>(dst + g * 32 + q * 8) = v;
    }
}

// ---- Pass 2: w[oc][ic][kh][kw] f32 -> wt2 panels in LDS-image (swizzled) order ----
// wt2[oc_tile(2)][step(36)=pos*4+icc][slot(512)][8]
//   slot s -> row=s>>2 (oc&127), fq=(s&3)^((row>>1)&3); covers ic = icc*32+fq*8+e
__global__ __launch_bounds__(256) void wt_kernel(const float* __restrict__ w,
                                                 ushort_t* __restrict__ wt2) {
    const int tid = blockIdx.x * 256 + threadIdx.x;   // 144 blocks -> 36864 slots
    const int panel = tid >> 9;
    const int s = tid & 511;
    const int oc_tile = panel / 36;
    const int rem = panel - oc_tile * 36;
    const int pos = rem >> 2;
    const int icc = rem & 3;
    const int row = s >> 2;
    const int fq = (s & 3) ^ ((row >> 1) & 3);
    const int oc = oc_tile * 128 + row;
    const int ic0 = icc * 32 + fq * 8;
    short8 v;
#pragma unroll
    for (int e = 0; e < 8; ++e) v[e] = (short)f2b(w[(oc * 128 + ic0 + e) * 9 + pos]);
    *reinterpret_cast<short8*>(wt2 + (size_t)tid * 8) = v;
}

// ---- Pass 3: implicit GEMM, 128x128 tile, BK=32, gload_lds + 2-phase dbuf ----
__global__ __launch_bounds__(256, 2) void conv_main(const ushort_t* __restrict__ xt,
                                                    const ushort_t* __restrict__ wt2,
                                                    const float* __restrict__ bias,
                                                    float* __restrict__ out) {
    __shared__ ushort_t lds[2][2][4096];   // [buf][A/B][slot*8] = 32 KB

    const int bid = blockIdx.x;
    const int work = (bid & 7) * 196 + (bid >> 3);   // XCD-bijective (1568 = 8*196)
    const int oc_tile = work & 1;
    const int P0 = (work >> 1) * 128;

    const int t = threadIdx.x;
    const int w = t >> 6;
    const int l = t & 63;
    const int fr = l & 15;
    const int fq = l >> 4;
    const int wr = w >> 1;
    const int wc = w & 1;

    // A source: panels already in LDS-image order; chunk c=w slot = c*64+l = t
    const ushort_t* Abase = wt2 + (size_t)oc_tile * (36 * 4096) + t * 8;

    // B source: per-thread pixel rows (chunks c=w and c=w+4)
    const int pa = w * 16 + (l >> 2);
    const int Pa = P0 + pa;
    const int na = Pa / HW2; const int hwa = Pa - na * HW2;
    const int oha = hwa / HWSZ; const int owa = hwa - oha * HWSZ;
    const int Pb = Pa + 64;
    const int nb = Pb / HW2; const int hwb = Pb - nb * HW2;
    const int ohb = hwb / HWSZ; const int owb = hwb - ohb * HWSZ;
    const ushort_t* xra = xt + (((size_t)na * PADW + oha) * PADW + owa) * INC;
    const ushort_t* xrb = xt + (((size_t)nb * PADW + ohb) * PADW + owb) * INC;
    const int swz = ((l & 3) ^ ((l >> 3) & 3)) * 8;   // elems; same for pa/pb (+64)

    // fragment read offset (elems): row=..+fr, chunk fq^((fr>>1)&3) -> 2-way max
    const int frag_off = fr * 32 + ((fq ^ ((fr >> 1) & 3)) * 8);

    f32x4 acc[4][4];
#pragma unroll
    for (int i = 0; i < 4; ++i)
#pragma unroll
        for (int j = 0; j < 4; ++j) { f32x4 z = {0.f,0.f,0.f,0.f}; acc[i][j] = z; }

    // prologue: stage step 0 (pos=0,icc=0 -> koff=0)
    glds16(Abase,            &lds[0][0][w * 512]);
    glds16(Abase + 2048,     &lds[0][0][(w + 4) * 512]);
    glds16(xra + swz,        &lds[0][1][w * 512]);
    glds16(xrb + swz,        &lds[0][1][(w + 4) * 512]);
    __syncthreads();

    int cur = 0;
    for (int s = 0; s < 36; ++s) {
        if (s < 35) {                       // stage next step into other buffer
            const int s1 = s + 1;
            const int pos = s1 >> 2;
            const int icc = s1 & 3;
            const int kh = pos / 3;
            const int kw = pos - kh * 3;
            const int koff = (kh * PADW + kw) * INC + icc * 32;
            const ushort_t* Ab = Abase + s1 * 4096;
            glds16(Ab,               &lds[cur ^ 1][0][w * 512]);
            glds16(Ab + 2048,        &lds[cur ^ 1][0][(w + 4) * 512]);
            glds16(xra + koff + swz, &lds[cur ^ 1][1][w * 512]);
            glds16(xrb + koff + swz, &lds[cur ^ 1][1][(w + 4) * 512]);
        }
        const ushort_t* A = &lds[cur][0][0];
        const ushort_t* B = &lds[cur][1][0];
        short8 af[4], bf[4];
#pragma unroll
        for (int mi = 0; mi < 4; ++mi)
            af[mi] = *reinterpret_cast<const short8*>(A + wr * 2048 + mi * 512 + frag_off);
#pragma unroll
        for (int ni = 0; ni < 4; ++ni)
            bf[ni] = *reinterpret_cast<const short8*>(B + wc * 2048 + ni * 512 + frag_off);
#pragma unroll
        for (int mi = 0; mi < 4; ++mi)
#pragma unroll
            for (int ni = 0; ni < 4; ++ni)
                acc[mi][ni] = __builtin_amdgcn_mfma_f32_16x16x32_bf16(af[mi], bf[ni],
                                                                      acc[mi][ni], 0, 0, 0);
        __syncthreads();   // drains vmcnt(0): next buf staged; lgkm: reads done
        cur ^= 1;
    }

    // epilogue: D row(oc)=fq*4+r, col(pix)=fr
    const int oc0 = oc_tile * 128;
    float bmr[4][4];
#pragma unroll
    for (int mi = 0; mi < 4; ++mi)
#pragma unroll
        for (int r = 0; r < 4; ++r)
            bmr[mi][r] = bias[oc0 + wr * 64 + mi * 16 + fq * 4 + r];

#pragma unroll
    for (int ni = 0; ni < 4; ++ni) {
        const int Pp = P0 + wc * 64 + ni * 16 + fr;
        const int nn = Pp / HW2;
        const int hwp = Pp - nn * HW2;
        float* op = out + (size_t)nn * (OUTC * HW2) + hwp;
#pragma unroll
        for (int mi = 0; mi < 4; ++mi)
#pragma unroll
            for (int r = 0; r < 4; ++r) {
                const int oc = oc0 + wr * 64 + mi * 16 + fq * 4 + r;
                op[oc * HW2] = acc[mi][ni][r] + bmr[mi][r];
            }
    }
}

extern "C" void kernel_launch(void* const* d_in, const int* in_sizes, int n_in,
                              void* d_out, int out_size, void* d_ws, size_t ws_size,
                              hipStream_t stream) {
    const float* x = (const float*)d_in[0];
    const float* w = (const float*)d_in[1];
    const float* bias = (const float*)d_in[2];
    float* out = (float*)d_out;

    ushort_t* xt = (ushort_t*)d_ws;            // 27,557,888 B (halo-padded)
    ushort_t* wt2 = xt + XT_ELEMS;             // 589,824 B

    hipMemsetAsync(d_ws, 0, XT_BYTES, stream);          // zero halo (and interior)
    xt_kernel<<<1568, 256, 0, stream>>>(x, xt);
    wt_kernel<<<144, 256, 0, stream>>>(w, wt2);
    conv_main<<<1568, 256, 0, stream>>>(xt, wt2, bias, out);
}

// Round 8
// 203.440 us; speedup vs baseline: 1.0817x; 1.0044x over previous
//
#include <hip/hip_runtime.h>

// Conv2d: N=32, Cin=128, H=W=56, Cout=256, K=3, s=1, p=1. fp32 in/out, bf16 MFMA.
// R5: 3-deep LDS pipeline with counted s_waitcnt vmcnt(4) across raw s_barrier
//     (T3/T4), s_setprio around MFMA cluster (T5), halo-zero instead of memset.

typedef __attribute__((ext_vector_type(8))) short short8;   // 8 bf16
typedef __attribute__((ext_vector_type(4))) float f32x4;
typedef unsigned short ushort_t;

#define HWSZ 56
#define HW2 3136
#define INC 128
#define OUTC 256
#define PADW 58
#define XT_ELEMS 13778944          // 32*58*58*128

__device__ __forceinline__ ushort_t f2b(float f) {
    union { float f; unsigned u; } v; v.f = f;
    unsigned r = v.u + 0x7fffu + ((v.u >> 16) & 1u);   // RNE
    return (ushort_t)(r >> 16);
}

__device__ __forceinline__ void glds16(const void* g, void* l) {
    __builtin_amdgcn_global_load_lds(
        (const __attribute__((address_space(1))) unsigned*)g,
        (__attribute__((address_space(3))) unsigned*)l, 16, 0, 0);
}

// ---- Pass 0: zero only the halo ring of xt (1.87 MB vs 27.5 MB memset) ----
__global__ __launch_bounds__(256) void halo_zero(ushort_t* __restrict__ xt) {
    const int tid = blockIdx.x * 256 + threadIdx.x;   // 456 blocks = 116736
    const int g = tid & 15;
    const int p = tid >> 4;            // 0..7295
    const int n = p / 228;
    const int bp = p - n * 228;
    int h, wv;
    if (bp < 58)       { h = 0;        wv = bp; }
    else if (bp < 116) { h = 57;       wv = bp - 58; }
    else if (bp < 172) { h = bp - 115; wv = 0; }     // 1..56
    else               { h = bp - 171; wv = 57; }    // 1..56
    const short8 z = {0,0,0,0,0,0,0,0};
    *reinterpret_cast<short8*>(xt + (((size_t)n * PADW + h) * PADW + wv) * INC + g * 8) = z;
}

// ---- Pass 1: x[n][c][h][w] f32 -> xt[n][h+1][w+1][c] bf16 ----
__global__ __launch_bounds__(256) void xt_kernel(const float* __restrict__ x,
                                                 ushort_t* __restrict__ xt) {
    __shared__ float tile[128][65];
    const int b = blockIdx.x;          // 32*49
    const int n = b / 49;
    const int hw0 = (b - n * 49) * 64;
    const int t = threadIdx.x;

    const float* xp = x + (size_t)n * (INC * HW2) + hw0;
    const int c_base = t >> 4;
    const int hwo = (t & 15) * 4;
#pragma unroll
    for (int j = 0; j < 8; ++j) {
        const int c = j * 16 + c_base;
        const f32x4 v = *reinterpret_cast<const f32x4*>(xp + c * HW2 + hwo);
        tile[c][hwo + 0] = v[0];
        tile[c][hwo + 1] = v[1];
        tile[c][hwo + 2] = v[2];
        tile[c][hwo + 3] = v[3];
    }
    __syncthreads();
    const int hw = t >> 2;
    const int q = t & 3;
    const int P = hw0 + hw;
    const int oh = P / HWSZ;
    const int ow = P - oh * HWSZ;
    ushort_t* dst = xt + (((size_t)n * PADW + oh + 1) * PADW + (ow + 1)) * INC;
#pragma unroll
    for (int g = 0; g < 4; ++g) {
        short8 v;
#pragma unroll
        for (int e = 0; e < 8; ++e) v[e] = (short)f2b(tile[g * 32 + q * 8 + e][hw]);
        *reinterpret_cast<short8*>(dst + g * 32 + q * 8) = v;
    }
}

// ---- Pass 2: w[oc][ic][kh][kw] f32 -> wt2 panels in LDS-image (swizzled) order ----
__global__ __launch_bounds__(256) void wt_kernel(const float* __restrict__ w,
                                                 ushort_t* __restrict__ wt2) {
    const int tid = blockIdx.x * 256 + threadIdx.x;   // 144 blocks
    const int panel = tid >> 9;
    const int s = tid & 511;
    const int oc_tile = panel / 36;
    const int rem = panel - oc_tile * 36;
    const int pos = rem >> 2;
    const int icc = rem & 3;
    const int row = s >> 2;
    const int fq = (s & 3) ^ ((row >> 1) & 3);
    const int oc = oc_tile * 128 + row;
    const int ic0 = icc * 32 + fq * 8;
    short8 v;
#pragma unroll
    for (int e = 0; e < 8; ++e) v[e] = (short)f2b(w[(oc * 128 + ic0 + e) * 9 + pos]);
    *reinterpret_cast<short8*>(wt2 + (size_t)tid * 8) = v;
}

// ---- Pass 3: implicit GEMM, 128x128 tile, BK=32, 3-deep counted-vmcnt pipeline ----
__global__ __launch_bounds__(256, 3) void conv_main(const ushort_t* __restrict__ xt,
                                                    const ushort_t* __restrict__ wt2,
                                                    const float* __restrict__ bias,
                                                    float* __restrict__ out) {
    __shared__ ushort_t lds[3][2][4096];   // 48 KB -> 3 blocks/CU

    const int bid = blockIdx.x;
    const int work = (bid & 7) * 196 + (bid >> 3);   // XCD-bijective (1568 = 8*196)
    const int oc_tile = work & 1;
    const int P0 = (work >> 1) * 128;

    const int t = threadIdx.x;
    const int w = t >> 6;
    const int l = t & 63;
    const int fr = l & 15;
    const int fq = l >> 4;
    const int wr = w >> 1;
    const int wc = w & 1;

    const ushort_t* Abase = wt2 + (size_t)oc_tile * (36 * 4096) + t * 8;

    const int pa = w * 16 + (l >> 2);
    const int Pa = P0 + pa;
    const int na = Pa / HW2; const int hwa = Pa - na * HW2;
    const int oha = hwa / HWSZ; const int owa = hwa - oha * HWSZ;
    const int Pb = Pa + 64;
    const int nb = Pb / HW2; const int hwb = Pb - nb * HW2;
    const int ohb = hwb / HWSZ; const int owb = hwb - ohb * HWSZ;
    const ushort_t* xra = xt + (((size_t)na * PADW + oha) * PADW + owa) * INC;
    const ushort_t* xrb = xt + (((size_t)nb * PADW + ohb) * PADW + owb) * INC;
    const int swz = ((l & 3) ^ ((l >> 3) & 3)) * 8;

    const int frag_off = fr * 32 + ((fq ^ ((fr >> 1) & 3)) * 8);

    f32x4 acc[4][4];
#pragma unroll
    for (int i = 0; i < 4; ++i)
#pragma unroll
        for (int j = 0; j < 4; ++j) { f32x4 z = {0.f,0.f,0.f,0.f}; acc[i][j] = z; }

    auto stage = [&](int s1, int bsel) {
        const int pos = s1 >> 2;
        const int icc = s1 & 3;
        const int kh = pos / 3;
        const int kw = pos - kh * 3;
        const int koff = (kh * PADW + kw) * INC + icc * 32;
        const ushort_t* Ab = Abase + s1 * 4096;
        glds16(Ab,               &lds[bsel][0][w * 512]);
        glds16(Ab + 2048,        &lds[bsel][0][(w + 4) * 512]);
        glds16(xra + koff + swz, &lds[bsel][1][w * 512]);
        glds16(xrb + koff + swz, &lds[bsel][1][(w + 4) * 512]);
    };

    auto compute = [&](int bsel) {
        const ushort_t* A = &lds[bsel][0][0];
        const ushort_t* B = &lds[bsel][1][0];
        short8 af[4], bf[4];
#pragma unroll
        for (int mi = 0; mi < 4; ++mi)
            af[mi] = *reinterpret_cast<const short8*>(A + wr * 2048 + mi * 512 + frag_off);
#pragma unroll
        for (int ni = 0; ni < 4; ++ni)
            bf[ni] = *reinterpret_cast<const short8*>(B + wc * 2048 + ni * 512 + frag_off);
        __builtin_amdgcn_s_setprio(1);
#pragma unroll
        for (int mi = 0; mi < 4; ++mi)
#pragma unroll
            for (int ni = 0; ni < 4; ++ni)
                acc[mi][ni] = __builtin_amdgcn_mfma_f32_16x16x32_bf16(af[mi], bf[ni],
                                                                      acc[mi][ni], 0, 0, 0);
        __builtin_amdgcn_s_setprio(0);
    };

    // prologue: 2 buffers in flight (8 outstanding loads)
    stage(0, 0);
    stage(1, 1);

    int bc = 0, bn = 2;
    for (int s = 0; s < 35; ++s) {
        // wait own oldest 4 (buf bc staged at s-2) -> leaves next buf's 4 in flight
        asm volatile("s_waitcnt vmcnt(4)\n\ts_barrier" ::: "memory");
        if (s < 34) stage(s + 2, bn);
        compute(bc);
        bc = (bc == 2) ? 0 : bc + 1;
        bn = (bn == 2) ? 0 : bn + 1;
    }
    // final step: drain
    asm volatile("s_waitcnt vmcnt(0)\n\ts_barrier" ::: "memory");
    compute(bc);

    // epilogue: D row(oc)=fq*4+r, col(pix)=fr
    const int oc0 = oc_tile * 128;
    float bmr[4][4];
#pragma unroll
    for (int mi = 0; mi < 4; ++mi)
#pragma unroll
        for (int r = 0; r < 4; ++r)
            bmr[mi][r] = bias[oc0 + wr * 64 + mi * 16 + fq * 4 + r];

#pragma unroll
    for (int ni = 0; ni < 4; ++ni) {
        const int Pp = P0 + wc * 64 + ni * 16 + fr;
        const int nn = Pp / HW2;
        const int hwp = Pp - nn * HW2;
        float* op = out + (size_t)nn * (OUTC * HW2) + hwp;
#pragma unroll
        for (int mi = 0; mi < 4; ++mi)
#pragma unroll
            for (int r = 0; r < 4; ++r) {
                const int oc = oc0 + wr * 64 + mi * 16 + fq * 4 + r;
                op[oc * HW2] = acc[mi][ni][r] + bmr[mi][r];
            }
    }
}

extern "C" void kernel_launch(void* const* d_in, const int* in_sizes, int n_in,
                              void* d_out, int out_size, void* d_ws, size_t ws_size,
                              hipStream_t stream) {
    const float* x = (const float*)d_in[0];
    const float* w = (const float*)d_in[1];
    const float* bias = (const float*)d_in[2];
    float* out = (float*)d_out;

    ushort_t* xt = (ushort_t*)d_ws;            // 27,557,888 B (halo-padded)
    ushort_t* wt2 = xt + XT_ELEMS;             // 589,824 B

    halo_zero<<<456, 256, 0, stream>>>(xt);
    xt_kernel<<<1568, 256, 0, stream>>>(x, xt);
    wt_kernel<<<144, 256, 0, stream>>>(w, wt2);
    conv_main<<<1568, 256, 0, stream>>>(xt, wt2, bias, out);
}